// Round 8
// baseline (252.935 us; speedup 1.0000x reference)
//
#include <hip/hip_runtime.h>
#include <hip/hip_bf16.h>
#include <stdint.h>

#define B_     8
#define TT     1024
#define DIM_   2048
#define S_     512
#define H_     16
#define DH     64
#define HID    1024

typedef _Float16 half8 __attribute__((ext_vector_type(8)));
typedef _Float16 half4v __attribute__((ext_vector_type(4)));
typedef float f32x4 __attribute__((ext_vector_type(4)));

__device__ __forceinline__ void gload_lds16(const void* g, void* l) {
  __builtin_amdgcn_global_load_lds(
      (__attribute__((address_space(1))) unsigned int*)(uintptr_t)g,
      (__attribute__((address_space(3))) unsigned int*)l, 16, 0, 0);
}

// ---------------- LayerNorm + cast to fp16 ----------------
__global__ __launch_bounds__(256) void ln_cast(
    const float* __restrict__ x, const float* __restrict__ gamma,
    const float* __restrict__ beta, _Float16* __restrict__ xn)
{
  const int row = blockIdx.x;
  const int tid = threadIdx.x;
  const float* xr = x + (size_t)row * DIM_;
  float4 a = ((const float4*)xr)[tid * 2];
  float4 b = ((const float4*)xr)[tid * 2 + 1];
  float s1 = a.x + a.y + a.z + a.w + b.x + b.y + b.z + b.w;
  float s2 = a.x*a.x + a.y*a.y + a.z*a.z + a.w*a.w
           + b.x*b.x + b.y*b.y + b.z*b.z + b.w*b.w;
  #pragma unroll
  for (int d = 1; d < 64; d <<= 1) {
    s1 += __shfl_xor(s1, d, 64);
    s2 += __shfl_xor(s2, d, 64);
  }
  __shared__ float red[8];
  const int w = tid >> 6, lane = tid & 63;
  if (lane == 0) { red[w] = s1; red[4 + w] = s2; }
  __syncthreads();
  s1 = red[0] + red[1] + red[2] + red[3];
  s2 = red[4] + red[5] + red[6] + red[7];
  const float mu  = s1 * (1.0f / DIM_);
  const float var = s2 * (1.0f / DIM_) - mu * mu;
  const float rs  = rsqrtf(var + 1e-5f);
  float4 g0 = ((const float4*)gamma)[tid * 2];
  float4 g1 = ((const float4*)gamma)[tid * 2 + 1];
  float4 e0 = ((const float4*)beta)[tid * 2];
  float4 e1 = ((const float4*)beta)[tid * 2 + 1];
  half8 o;
  o[0] = (_Float16)((a.x - mu) * rs * g0.x + e0.x);
  o[1] = (_Float16)((a.y - mu) * rs * g0.y + e0.y);
  o[2] = (_Float16)((a.z - mu) * rs * g0.z + e0.z);
  o[3] = (_Float16)((a.w - mu) * rs * g0.w + e0.w);
  o[4] = (_Float16)((b.x - mu) * rs * g1.x + e1.x);
  o[5] = (_Float16)((b.y - mu) * rs * g1.y + e1.y);
  o[6] = (_Float16)((b.z - mu) * rs * g1.z + e1.z);
  o[7] = (_Float16)((b.w - mu) * rs * g1.w + e1.w);
  *(half8*)(xn + (size_t)row * DIM_ + tid * 8) = o;
}

// ---------------- elementwise f32 -> f16 cast ----------------
__global__ __launch_bounds__(256) void cast_f16(
    const float* __restrict__ in, _Float16* __restrict__ out, int n4)
{
  int i = blockIdx.x * 256 + threadIdx.x;
  if (i >= n4) return;
  float4 v = ((const float4*)in)[i];
  half4v o;
  o[0] = (_Float16)v.x; o[1] = (_Float16)v.y;
  o[2] = (_Float16)v.z; o[3] = (_Float16)v.w;
  ((half4v*)out)[i] = o;
}

// ---------------- transpose + cast: in[R][C] f32 -> out[C][R] f16 ----------------
__global__ void transpose_cast(const float* __restrict__ in,
                               _Float16* __restrict__ out, int R, int C)
{
  __shared__ float t[32][33];
  const int c0 = blockIdx.x * 32, r0 = blockIdx.y * 32;
  const int tx = threadIdx.x, ty = threadIdx.y;
  #pragma unroll
  for (int i = 0; i < 32; i += 8)
    t[ty + i][tx] = in[(size_t)(r0 + ty + i) * C + c0 + tx];
  __syncthreads();
  #pragma unroll
  for (int i = 0; i < 32; i += 8)
    out[(size_t)(c0 + ty + i) * R + r0 + tx] = (_Float16)t[tx][ty + i];
}

// ---------------- V^T builder: kv[B*S][2048] cols 1024+ -> vt[B][H][DH][S] ----------------
__global__ void build_vt(const _Float16* __restrict__ kv, _Float16* __restrict__ vt)
{
  __shared__ _Float16 t[64][65];
  const int s0 = blockIdx.x * 64;
  const int h = blockIdx.y, b = blockIdx.z;
  const int tx = threadIdx.x, ty = threadIdx.y;
  const _Float16* src = kv + (size_t)(b * S_) * 2048 + HID + h * DH;
  #pragma unroll
  for (int i = 0; i < 64; i += 8)
    t[ty + i][tx] = src[(size_t)(s0 + ty + i) * 2048 + tx];
  __syncthreads();
  _Float16* dst = vt + (size_t)((b * H_ + h) * DH) * S_;
  #pragma unroll
  for (int i = 0; i < 64; i += 8)
    dst[(size_t)(ty + i) * S_ + s0 + tx] = t[tx][ty + i];
}

// ---------------- 256x256 GEMM, BK=64, 8 waves, 4-phase interleave ---------
// C[M][N] = A[M][K] @ BT[N][K]^T.  8-phase-style schedule (T3+T4): per K-tile
// 4 phases of {ds_read subtile | stage-issue | barrier | 16 MFMA | barrier}.
// Stage stream runs 4-7 phases ahead of first use:
//   A(t+1) rows 64-127,192-255 @ t.ph0 ; B(t+1) lo @ t.ph1 ; B(t+1) hi +
//   A(t+2) rows 0-63,128-191 @ t.ph2.  Guard: vmcnt(2) at end of t.ph3
//   (allows only the 2 A(t+2)-early loads), vmcnt(0) at tail. All LDS region
//   overwrites are >=1 barrier after their last reader (verified per 64-row
//   round). XOR-chunk swizzle via pre-swizzled global source (0 conflicts).
template<int KD, int ND, typename OutT>
__device__ __forceinline__ void gemm256_body(
    const _Float16* __restrict__ A, const _Float16* __restrict__ BT,
    OutT* __restrict__ C, int m0, int n0,
    _Float16* __restrict__ sA0, _Float16* __restrict__ sA1,
    _Float16* __restrict__ sB0, _Float16* __restrict__ sB1)
{
  constexpr int NT = KD / 64;                 // >= 16 here
  const int tid = threadIdx.x;
  const int lane = tid & 63, w = tid >> 6;
  const int l15 = lane & 15, lhi = lane >> 4;
  const int wr = w >> 2, wc = w & 3;          // 2 x 4 wave grid
  const int srow = lane >> 3;                 // row & 7 within 8-row group
  const int sj   = (lane & 7) ^ srow;         // pre-swizzled source chunk

  // stage one 64-row round j (0..3) of tile kt into dst
  auto stA = [&](int kt, int j, _Float16* dst) {
    const int r = j * 64 + w * 8 + srow;
    gload_lds16(A + (size_t)(m0 + r) * KD + kt * 64 + sj * 8,
                dst + (j * 64 + w * 8) * 64);
  };
  auto stB = [&](int kt, int j, _Float16* dst) {
    const int r = j * 64 + w * 8 + srow;
    gload_lds16(BT + (size_t)(n0 + r) * KD + kt * 64 + sj * 8,
                dst + (j * 64 + w * 8) * 64);
  };

  f32x4 acc[8][4] = {};
  _Float16* bufA[2] = {sA0, sA1};
  _Float16* bufB[2] = {sB0, sB1};

  // prologue: tile0 fully + A(1)-early; guard tile0 with vmcnt(2)
  #pragma unroll
  for (int j = 0; j < 4; ++j) stA(0, j, sA0);
  #pragma unroll
  for (int j = 0; j < 4; ++j) stB(0, j, sB0);
  stA(1, 0, sA1); stA(1, 2, sA1);
  asm volatile("s_waitcnt vmcnt(2)" ::: "memory");
  __builtin_amdgcn_sched_barrier(0);
  __builtin_amdgcn_s_barrier();
  __builtin_amdgcn_sched_barrier(0);

  for (int kt = 0; kt < NT; ++kt) {
    _Float16* cA = bufA[kt & 1];
    _Float16* cB = bufB[kt & 1];
    _Float16* nA = bufA[(kt + 1) & 1];
    _Float16* nB = bufB[(kt + 1) & 1];
    half8 bf[4][2];
    #pragma unroll
    for (int p = 0; p < 4; ++p) {
      // --- ds-read this phase's register subtile ---
      half8 af[2][2];
      #pragma unroll
      for (int i = 0; i < 2; ++i) {
        const int row = wr * 128 + (p * 2 + i) * 16 + l15;
        #pragma unroll
        for (int kh = 0; kh < 2; ++kh)
          af[i][kh] = *(const half8*)&cA[row * 64 + (((kh * 4 + lhi) ^ (l15 & 7)) * 8)];
      }
      if (p == 0) {
        #pragma unroll
        for (int nf = 0; nf < 4; ++nf) {
          const int row = wc * 64 + nf * 16 + l15;
          #pragma unroll
          for (int kh = 0; kh < 2; ++kh)
            bf[nf][kh] = *(const half8*)&cB[row * 64 + (((kh * 4 + lhi) ^ (l15 & 7)) * 8)];
        }
      }
      // --- stage issues (in flight across barriers; counted at ph3) ---
      if (p == 0 && kt + 1 < NT) { stA(kt + 1, 1, nA); stA(kt + 1, 3, nA); }
      if (p == 1 && kt + 1 < NT) { stB(kt + 1, 0, nB); stB(kt + 1, 1, nB); }
      if (p == 2) {
        if (kt + 1 < NT) { stB(kt + 1, 2, nB); stB(kt + 1, 3, nB); }
        if (kt + 2 < NT) { stA(kt + 2, 0, cA); stA(kt + 2, 2, cA); }
      }
      __builtin_amdgcn_sched_barrier(0);
      __builtin_amdgcn_s_barrier();
      __builtin_amdgcn_sched_barrier(0);
      // --- 16 MFMA (this phase's 2 m-frags x 4 n-frags x 2 k-halves) ---
      __builtin_amdgcn_s_setprio(1);
      #pragma unroll
      for (int kh = 0; kh < 2; ++kh)
        #pragma unroll
        for (int i = 0; i < 2; ++i)
          #pragma unroll
          for (int nf = 0; nf < 4; ++nf)
            acc[p * 2 + i][nf] = __builtin_amdgcn_mfma_f32_16x16x32_f16(
                af[i][kh], bf[nf][kh], acc[p * 2 + i][nf], 0, 0, 0);
      __builtin_amdgcn_s_setprio(0);
      // --- tile guard at end of ph3: next tile's data must be resident ---
      if (p == 3 && kt + 1 < NT) {
        if (kt + 2 < NT) asm volatile("s_waitcnt vmcnt(2)" ::: "memory");
        else             asm volatile("s_waitcnt vmcnt(0)" ::: "memory");
      }
      __builtin_amdgcn_sched_barrier(0);
      __builtin_amdgcn_s_barrier();
      __builtin_amdgcn_sched_barrier(0);
    }
  }

  #pragma unroll
  for (int mf = 0; mf < 8; ++mf) {
    const int row = m0 + wr * 128 + mf * 16 + lhi * 4;
    #pragma unroll
    for (int nf = 0; nf < 4; ++nf) {
      const int col = n0 + wc * 64 + nf * 16 + l15;
      #pragma unroll
      for (int r = 0; r < 4; ++r)
        C[(size_t)(row + r) * ND + col] = (OutT)acc[mf][nf][r];
    }
  }
}

// Fused Q-proj (128 blocks) + KV-proj (128 blocks): 256 blocks = 1/CU.
// XCD-bijective: xcd = id&7; same-XCD blocks share A m-panels across all n.
__global__ __launch_bounds__(512, 2) void gemm_qkv(
    const _Float16* __restrict__ xn, const _Float16* __restrict__ wqT,
    _Float16* __restrict__ qh,
    const _Float16* __restrict__ mediah, const _Float16* __restrict__ wkvT,
    _Float16* __restrict__ kvh)
{
  __shared__ __align__(16) _Float16 sA0[256 * 64], sA1[256 * 64];
  __shared__ __align__(16) _Float16 sB0[256 * 64], sB1[256 * 64];
  const int id = blockIdx.x;
  const int x = id & 7, k = id >> 4;
  if (((id >> 3) & 1) == 0) {
    const int n = k & 3, m = (k >> 2) * 8 + x;          // M=8192,N=1024,K=2048
    gemm256_body<2048, 1024, _Float16>(xn, wqT, qh, m * 256, n * 256,
                                       sA0, sA1, sB0, sB1);
  } else {
    const int n = k & 7, m = (k >> 3) * 8 + x;          // M=4096,N=2048,K=1024
    gemm256_body<1024, 2048, _Float16>(mediah, wkvT, kvh, m * 256, n * 256,
                                       sA0, sA1, sB0, sB1);
  }
}

// Out-proj: M=8192, N=2048, K=1024 -> 256 blocks = 1/CU, f32 out.
__global__ __launch_bounds__(512, 2) void gemm_out(
    const _Float16* __restrict__ aoh, const _Float16* __restrict__ woT,
    float* __restrict__ out)
{
  __shared__ __align__(16) _Float16 sA0[256 * 64], sA1[256 * 64];
  __shared__ __align__(16) _Float16 sB0[256 * 64], sB1[256 * 64];
  const int id = blockIdx.x;
  const int x = id & 7, k = id >> 3;
  const int n = k & 7, m = (k >> 3) * 8 + x;
  gemm256_body<1024, 2048, float>(aoh, woT, out, m * 256, n * 256,
                                  sA0, sA1, sB0, sB1);
}

// ---------------- fused attention v6: swapped QK^T, lane-local softmax ----
__global__ __launch_bounds__(512, 6) void attn_kernel(
    const _Float16* __restrict__ q, const _Float16* __restrict__ kv,
    const _Float16* __restrict__ vt, _Float16* __restrict__ ao)
{
  __shared__ __align__(16) _Float16 Ks[2][64 * 64];   // 8 KB each
  __shared__ __align__(16) _Float16 Vs[2][64 * 64];   // 8 KB each
  __shared__ __align__(16) _Float16 P[8][16 * 64];    // 16 KB (per-wave 2KB)
  const int tid = threadIdx.x;
  const int lane = tid & 63, w = tid >> 6;
  const int l15 = lane & 15, lhi = lane >> 4;
  const int id = blockIdx.x;
  const int bh = id & 127, tb = id >> 7;
  const int b = bh >> 4, h = bh & 15;
  const int t0 = tb * 128 + w * 16;

  const _Float16* qp = q + (size_t)(b * TT + t0 + l15) * HID + h * DH + lhi * 8;
  half8 aq0 = *(const half8*)qp;
  half8 aq1 = *(const half8*)(qp + 32);

  const int srow = lane >> 3;
  const int sj   = (lane & 7) ^ srow;
  const _Float16* kbase = kv + (size_t)(b * S_) * 2048 + h * DH;
  const _Float16* vbase = vt + (size_t)((b * H_ + h) * DH) * S_;

  auto stageK = [&](int c, int pg) {
    const int r = w * 8 + srow;
    gload_lds16(kbase + (size_t)(c * 64 + r) * 2048 + sj * 8, &Ks[pg][w * 512]);
  };
  auto stageV = [&](int c, int pg) {
    const int r = w * 8 + srow;
    gload_lds16(vbase + (size_t)r * S_ + c * 64 + sj * 8, &Vs[pg][w * 512]);
  };

  f32x4 acco[4] = {};
  float m_ = -1e30f, l_ = 0.f;           // per-lane state for q = l15

  const int key = l15 & 7;
  const int ck0 = lhi ^ key;
  const int swr = key << 3;

  stageK(0, 0); stageV(0, 0);
  __syncthreads();
  int cur = 0;
  for (int c = 0; c < 8; ++c) {
    if (c + 1 < 8) { stageK(c + 1, cur ^ 1); stageV(c + 1, cur ^ 1); }
    // --- QK^T swapped: accs row(reg)=s, col(l15)=q ---
    f32x4 accs[4] = {};
    __builtin_amdgcn_s_setprio(1);
    #pragma unroll
    for (int n = 0; n < 4; ++n) {
      const int row = n * 16 + l15;
      half8 kf0 = *(const half8*)&Ks[cur][row * 64 + ck0 * 8];
      half8 kf1 = *(const half8*)&Ks[cur][row * 64 + (ck0 ^ 4) * 8];
      accs[n] = __builtin_amdgcn_mfma_f32_16x16x32_f16(kf0, aq0, accs[n], 0, 0, 0);
      accs[n] = __builtin_amdgcn_mfma_f32_16x16x32_f16(kf1, aq1, accs[n], 0, 0, 0);
    }
    __builtin_amdgcn_s_setprio(0);
    // --- lane-local online softmax for q = l15 ---
    float c0 = fmaxf(fmaxf(accs[0][0], accs[0][1]), fmaxf(accs[0][2], accs[0][3]));
    float c1 = fmaxf(fmaxf(accs[1][0], accs[1][1]), fmaxf(accs[1][2], accs[1][3]));
    float c2 = fmaxf(fmaxf(accs[2][0], accs[2][1]), fmaxf(accs[2][2], accs[2][3]));
    float c3 = fmaxf(fmaxf(accs[3][0], accs[3][1]), fmaxf(accs[3][2], accs[3][3]));
    float mx = fmaxf(fmaxf(c0, c1), fmaxf(c2, c3));
    mx = fmaxf(mx, __shfl_xor(mx, 16, 64));
    mx = fmaxf(mx, __shfl_xor(mx, 32, 64));
    const float mnew = fmaxf(m_, mx);
    const float scale = __expf(m_ - mnew);
    m_ = mnew;
    #pragma unroll
    for (int n = 0; n < 4; ++n)
      #pragma unroll
      for (int r = 0; r < 4; ++r)
        accs[n][r] = __expf(accs[n][r] - mnew);
    float s0 = (accs[0][0] + accs[0][1]) + (accs[0][2] + accs[0][3]);
    float s1 = (accs[1][0] + accs[1][1]) + (accs[1][2] + accs[1][3]);
    float s2 = (accs[2][0] + accs[2][1]) + (accs[2][2] + accs[2][3]);
    float s3 = (accs[3][0] + accs[3][1]) + (accs[3][2] + accs[3][3]);
    float sm = (s0 + s1) + (s2 + s3);
    sm += __shfl_xor(sm, 16, 64);
    sm += __shfl_xor(sm, 32, 64);
    l_ = l_ * scale + sm;
    // --- P write: row q=l15, col s=n*16+lhi*4+r, half4, XOR-swizzled ---
    #pragma unroll
    for (int n = 0; n < 4; ++n) {
      half4v pw;
      pw[0] = (_Float16)accs[n][0]; pw[1] = (_Float16)accs[n][1];
      pw[2] = (_Float16)accs[n][2]; pw[3] = (_Float16)accs[n][3];
      const int base = (n * 16 + lhi * 4) ^ swr;
      *(half4v*)&P[w][l15 * 64 + base] = pw;
    }
    // --- acco rescale (broadcast from lane q) ---
    #pragma unroll
    for (int r = 0; r < 4; ++r) {
      const float s_r = __shfl(scale, (lane >> 4) * 4 + r, 16);
      #pragma unroll
      for (int n = 0; n < 4; ++n) acco[n][r] *= s_r;
    }
    // --- PV partial ---
    __builtin_amdgcn_s_setprio(1);
    #pragma unroll
    for (int ks = 0; ks < 2; ++ks) {
      half8 ap = *(const half8*)&P[w][l15 * 64 + ((ks * 32 + lhi * 8) ^ swr)];
      #pragma unroll
      for (int n = 0; n < 4; ++n) {
        const int row = n * 16 + l15;
        half8 vf = *(const half8*)&Vs[cur][row * 64 + ((ks * 4 + lhi) ^ key) * 8];
        acco[n] = __builtin_amdgcn_mfma_f32_16x16x32_f16(ap, vf, acco[n], 0, 0, 0);
      }
    }
    __builtin_amdgcn_s_setprio(0);
    __syncthreads();
    cur ^= 1;
  }
  // --- finalize: chunk-XOR staging (conflict-free read-back) ---
  const float inv = 1.0f / (l_ * 8.0f);
  #pragma unroll
  for (int r = 0; r < 4; ++r) {
    const float inv_r = __shfl(inv, (lane >> 4) * 4 + r, 16);
    const int qrow = lhi * 4 + r;
    const int kq = qrow & 7;
    #pragma unroll
    for (int n = 0; n < 4; ++n) {
      const int d = n * 16 + l15;
      P[w][qrow * 64 + (((d >> 3) ^ kq) * 8) + (d & 7)] =
          (_Float16)(acco[n][r] * inv_r);
    }
  }
  const int q2 = lane >> 2;
  const int kq2 = q2 & 7;
  const int g0 = ((lane & 3) * 2) ^ kq2;
  const int g1 = ((lane & 3) * 2 + 1) ^ kq2;
  half8 o0 = *(const half8*)&P[w][q2 * 64 + g0 * 8];
  half8 o1 = *(const half8*)&P[w][q2 * 64 + g1 * 8];
  _Float16* op = ao + (size_t)(b * TT + t0 + q2) * HID + h * DH + (lane & 3) * 16;
  *(half8*)op = o0;
  *(half8*)(op + 8) = o1;
}

extern "C" void kernel_launch(void* const* d_in, const int* in_sizes, int n_in,
                              void* d_out, int out_size, void* d_ws, size_t ws_size,
                              hipStream_t stream) {
  const float* x     = (const float*)d_in[0];
  const float* media = (const float*)d_in[1];
  // d_in[2] media_locations: unused (reference discards the mask)
  const float* Wq    = (const float*)d_in[3];
  const float* Wkv   = (const float*)d_in[4];
  const float* Wo    = (const float*)d_in[5];
  const float* gamma = (const float*)d_in[6];
  const float* beta  = (const float*)d_in[7];
  float* out = (float*)d_out;

  char* ws = (char*)d_ws;
  _Float16* xn     = (_Float16*)(ws);                    // 8192x2048 (32MB)
  _Float16* qh     = (_Float16*)(ws + 33554432);         // 8192x1024 (16MB)
  _Float16* kvh    = (_Float16*)(ws + 50331648);         // 4096x2048 (16MB)
  _Float16* aoh    = (_Float16*)(ws + 67108864);         // 8192x1024 (16MB)
  _Float16* vth    = (_Float16*)(ws + 83886080);         // 8x16x64x512 (8MB)
  _Float16* mediah = (_Float16*)(ws + 92274688);         // 4096x1024 (8MB)
  _Float16* wqT    = (_Float16*)(ws + 100663296);        // 1024x2048 (4MB)
  _Float16* wkvT   = (_Float16*)(ws + 104857600);        // 2048x1024 (4MB)
  _Float16* woT    = (_Float16*)(ws + 109051904);        // 2048x1024 (4MB)

  ln_cast<<<dim3(8192), dim3(256), 0, stream>>>(x, gamma, beta, xn);
  transpose_cast<<<dim3(1024/32, 2048/32), dim3(32, 8), 0, stream>>>(Wq,  wqT,  2048, 1024);
  transpose_cast<<<dim3(2048/32, 1024/32), dim3(32, 8), 0, stream>>>(Wkv, wkvT, 1024, 2048);
  transpose_cast<<<dim3(2048/32, 1024/32), dim3(32, 8), 0, stream>>>(Wo,  woT,  1024, 2048);
  cast_f16<<<dim3(4096), dim3(256), 0, stream>>>(media, mediah, 4194304 / 4);

  gemm_qkv<<<dim3(256), dim3(512), 0, stream>>>(xn, wqT, qh, mediah, wkvT, kvh);
  build_vt<<<dim3(8, 16, 8), dim3(64, 8), 0, stream>>>(kvh, vth);
  attn_kernel<<<dim3(1024), dim3(512), 0, stream>>>(qh, kvh, vth, aoh);
  gemm_out<<<dim3(256), dim3(512), 0, stream>>>(aoh, woT, out);
}

// Round 9
// 183.294 us; speedup vs baseline: 1.3799x; 1.3799x over previous
//
#include <hip/hip_runtime.h>
#include <hip/hip_bf16.h>
#include <stdint.h>

#define B_     8
#define TT     1024
#define DIM_   2048
#define S_     512
#define H_     16
#define DH     64
#define HID    1024

typedef _Float16 half8 __attribute__((ext_vector_type(8)));
typedef _Float16 half4v __attribute__((ext_vector_type(4)));
typedef float f32x4 __attribute__((ext_vector_type(4)));

__device__ __forceinline__ void gload_lds16(const void* g, void* l) {
  __builtin_amdgcn_global_load_lds(
      (__attribute__((address_space(1))) unsigned int*)(uintptr_t)g,
      (__attribute__((address_space(3))) unsigned int*)l, 16, 0, 0);
}

// ---------------- LayerNorm + cast to fp16 ----------------
__global__ __launch_bounds__(256) void ln_cast(
    const float* __restrict__ x, const float* __restrict__ gamma,
    const float* __restrict__ beta, _Float16* __restrict__ xn)
{
  const int row = blockIdx.x;
  const int tid = threadIdx.x;
  const float* xr = x + (size_t)row * DIM_;
  float4 a = ((const float4*)xr)[tid * 2];
  float4 b = ((const float4*)xr)[tid * 2 + 1];
  float s1 = a.x + a.y + a.z + a.w + b.x + b.y + b.z + b.w;
  float s2 = a.x*a.x + a.y*a.y + a.z*a.z + a.w*a.w
           + b.x*b.x + b.y*b.y + b.z*b.z + b.w*b.w;
  #pragma unroll
  for (int d = 1; d < 64; d <<= 1) {
    s1 += __shfl_xor(s1, d, 64);
    s2 += __shfl_xor(s2, d, 64);
  }
  __shared__ float red[8];
  const int w = tid >> 6, lane = tid & 63;
  if (lane == 0) { red[w] = s1; red[4 + w] = s2; }
  __syncthreads();
  s1 = red[0] + red[1] + red[2] + red[3];
  s2 = red[4] + red[5] + red[6] + red[7];
  const float mu  = s1 * (1.0f / DIM_);
  const float var = s2 * (1.0f / DIM_) - mu * mu;
  const float rs  = rsqrtf(var + 1e-5f);
  float4 g0 = ((const float4*)gamma)[tid * 2];
  float4 g1 = ((const float4*)gamma)[tid * 2 + 1];
  float4 e0 = ((const float4*)beta)[tid * 2];
  float4 e1 = ((const float4*)beta)[tid * 2 + 1];
  half8 o;
  o[0] = (_Float16)((a.x - mu) * rs * g0.x + e0.x);
  o[1] = (_Float16)((a.y - mu) * rs * g0.y + e0.y);
  o[2] = (_Float16)((a.z - mu) * rs * g0.z + e0.z);
  o[3] = (_Float16)((a.w - mu) * rs * g0.w + e0.w);
  o[4] = (_Float16)((b.x - mu) * rs * g1.x + e1.x);
  o[5] = (_Float16)((b.y - mu) * rs * g1.y + e1.y);
  o[6] = (_Float16)((b.z - mu) * rs * g1.z + e1.z);
  o[7] = (_Float16)((b.w - mu) * rs * g1.w + e1.w);
  *(half8*)(xn + (size_t)row * DIM_ + tid * 8) = o;
}

// ---------------- elementwise f32 -> f16 cast ----------------
__global__ __launch_bounds__(256) void cast_f16(
    const float* __restrict__ in, _Float16* __restrict__ out, int n4)
{
  int i = blockIdx.x * 256 + threadIdx.x;
  if (i >= n4) return;
  float4 v = ((const float4*)in)[i];
  half4v o;
  o[0] = (_Float16)v.x; o[1] = (_Float16)v.y;
  o[2] = (_Float16)v.z; o[3] = (_Float16)v.w;
  ((half4v*)out)[i] = o;
}

// ---------------- transpose + cast: in[R][C] f32 -> out[C][R] f16 ----------------
__global__ void transpose_cast(const float* __restrict__ in,
                               _Float16* __restrict__ out, int R, int C)
{
  __shared__ float t[32][33];
  const int c0 = blockIdx.x * 32, r0 = blockIdx.y * 32;
  const int tx = threadIdx.x, ty = threadIdx.y;
  #pragma unroll
  for (int i = 0; i < 32; i += 8)
    t[ty + i][tx] = in[(size_t)(r0 + ty + i) * C + c0 + tx];
  __syncthreads();
  #pragma unroll
  for (int i = 0; i < 32; i += 8)
    out[(size_t)(c0 + ty + i) * R + r0 + tx] = (_Float16)t[tx][ty + i];
}

// ---------------- 128x128 GEMM, BK=32, 4 waves, m97-style loop -------------
// C[M][N] = A[M][K] @ BT[N][K]^T. LDS 32KB (2buf x (A+B) x 128x32 f16) ->
// 4 blocks/CU (the proven occupancy regime; inter-block overlap hides the
// stage stall). One __syncthreads per K-tile (compiler emits the vmcnt/lgkm
// drain). XOR swizzle chunk ^= (row>>1)&3 on stage source + frag reads:
// residual 2-way only (free). No inline asm (m141 lesson).
template<typename OutT>
__device__ __forceinline__ void gemm128_body(
    const _Float16* __restrict__ A, const _Float16* __restrict__ BT,
    OutT* __restrict__ C, int KD, int ND, int m0, int n0,
    _Float16* __restrict__ sA, _Float16* __restrict__ sB)
{
  const int tid = threadIdx.x;
  const int lane = tid & 63, w = tid >> 6;
  const int l15 = lane & 15, lhi = lane >> 4;
  const int wr = w >> 1, wc = w & 1;
  const int rr = tid >> 2;                  // staging row 0..63 (+64 per round)
  const int sc = (tid & 3) ^ ((rr >> 1) & 3);  // pre-swizzled source chunk

  // stage 128x32 tile: 2 rounds of 64 rows; wave-uniform LDS dst (lane x 16B)
  auto stage = [&](const _Float16* __restrict__ G, int base, int k0,
                   _Float16* dst) {
    #pragma unroll
    for (int j = 0; j < 2; ++j) {
      const int r = j * 64 + rr;
      gload_lds16(G + (size_t)(base + r) * KD + k0 + sc * 8,
                  dst + j * 2048 + w * 512);
    }
  };

  f32x4 acc[4][4] = {};
  const int NT = KD >> 5;
  const int ck = lhi ^ ((l15 >> 1) & 3);    // swizzled read chunk

  stage(A, m0, 0, sA);
  stage(BT, n0, 0, sB);
  __syncthreads();
  int cur = 0;
  for (int kt = 0; kt < NT; ++kt) {
    if (kt + 1 < NT) {
      stage(A, m0, (kt + 1) * 32, sA + (cur ^ 1) * 4096);
      stage(BT, n0, (kt + 1) * 32, sB + (cur ^ 1) * 4096);
    }
    const _Float16* cA = sA + cur * 4096;
    const _Float16* cB = sB + cur * 4096;
    half8 af[4], bf[4];
    #pragma unroll
    for (int m = 0; m < 4; ++m)
      af[m] = *(const half8*)&cA[(wr * 64 + m * 16 + l15) * 32 + ck * 8];
    #pragma unroll
    for (int n = 0; n < 4; ++n)
      bf[n] = *(const half8*)&cB[(wc * 64 + n * 16 + l15) * 32 + ck * 8];
    #pragma unroll
    for (int m = 0; m < 4; ++m)
      #pragma unroll
      for (int n = 0; n < 4; ++n)
        acc[m][n] = __builtin_amdgcn_mfma_f32_16x16x32_f16(
            af[m], bf[n], acc[m][n], 0, 0, 0);
    __syncthreads();
    cur ^= 1;
  }

  #pragma unroll
  for (int m = 0; m < 4; ++m) {
    const int row = m0 + wr * 64 + m * 16 + lhi * 4;
    #pragma unroll
    for (int n = 0; n < 4; ++n) {
      const int col = n0 + wc * 64 + n * 16 + l15;
      #pragma unroll
      for (int r = 0; r < 4; ++r)
        C[(size_t)(row + r) * ND + col] = (OutT)acc[m][n][r];
    }
  }
}

// Fused Q-proj + K-proj + V^T-proj: 512+256+256 = 1024 blocks = 4/CU.
// V^T trick: vth[1024 d][4096 s] = WvT @ media^T via A=wkvT+1024*1024,
// BT=mediah -> V is produced already transposed (build_vt eliminated).
// XCD mapping: id = n*MT + m (m fastest) -> all n-tiles of an A m-panel
// land on XCD m%8 (sub-grid bases 512/768 are multiples of 8).
__global__ __launch_bounds__(256, 4) void gemm_qkv(
    const _Float16* __restrict__ xn, const _Float16* __restrict__ wqT,
    _Float16* __restrict__ qh,
    const _Float16* __restrict__ mediah, const _Float16* __restrict__ wkvT,
    _Float16* __restrict__ kh, _Float16* __restrict__ vth)
{
  __shared__ __align__(16) _Float16 sA[2 * 4096], sB[2 * 4096];
  const int id = blockIdx.x;
  if (id < 512) {              // Q: M=8192 N=1024 K=2048 (64 x 8 tiles)
    const int m = id & 63, n = id >> 6;
    gemm128_body<_Float16>(xn, wqT, qh, 2048, 1024, m * 128, n * 128, sA, sB);
  } else if (id < 768) {       // K: M=4096 N=1024 K=1024 (32 x 8 tiles)
    const int lid = id - 512;
    const int m = lid & 31, n = lid >> 5;
    gemm128_body<_Float16>(mediah, wkvT, kh, 1024, 1024, m * 128, n * 128, sA, sB);
  } else {                     // V^T: M=1024 N=4096 K=1024 (8 x 32 tiles)
    const int lid = id - 768;
    const int m = lid & 7, n = lid >> 3;
    gemm128_body<_Float16>(wkvT + 1024 * 1024, mediah, vth, 1024, 4096,
                           m * 128, n * 128, sA, sB);
  }
}

// Out-proj: M=8192 N=2048 K=1024 -> 64 x 16 = 1024 blocks = 4/CU, f32 out.
__global__ __launch_bounds__(256, 4) void gemm_out(
    const _Float16* __restrict__ aoh, const _Float16* __restrict__ woT,
    float* __restrict__ out)
{
  __shared__ __align__(16) _Float16 sA[2 * 4096], sB[2 * 4096];
  const int id = blockIdx.x;
  const int m = id & 63, n = id >> 6;
  gemm128_body<float>(aoh, woT, out, 1024, 2048, m * 128, n * 128, sA, sB);
}

// ---------------- fused attention v6: swapped QK^T, lane-local softmax ----
// (round-7 attn; K from kh [B*S][1024], V^T from vth [1024][4096])
__global__ __launch_bounds__(512, 6) void attn_kernel(
    const _Float16* __restrict__ q, const _Float16* __restrict__ kh,
    const _Float16* __restrict__ vt, _Float16* __restrict__ ao)
{
  __shared__ __align__(16) _Float16 Ks[2][64 * 64];   // 8 KB each
  __shared__ __align__(16) _Float16 Vs[2][64 * 64];   // 8 KB each
  __shared__ __align__(16) _Float16 P[8][16 * 64];    // 16 KB (per-wave 2KB)
  const int tid = threadIdx.x;
  const int lane = tid & 63, w = tid >> 6;
  const int l15 = lane & 15, lhi = lane >> 4;
  const int id = blockIdx.x;
  const int bh = id & 127, tb = id >> 7;
  const int b = bh >> 4, h = bh & 15;
  const int t0 = tb * 128 + w * 16;

  const _Float16* qp = q + (size_t)(b * TT + t0 + l15) * HID + h * DH + lhi * 8;
  half8 aq0 = *(const half8*)qp;
  half8 aq1 = *(const half8*)(qp + 32);

  const int srow = lane >> 3;
  const int sj   = (lane & 7) ^ srow;
  const _Float16* kbase = kh + (size_t)(b * S_) * 1024 + h * DH;
  const _Float16* vbase = vt + (size_t)(h * DH) * 4096 + b * S_;

  auto stageK = [&](int c, int pg) {
    const int r = w * 8 + srow;
    gload_lds16(kbase + (size_t)(c * 64 + r) * 1024 + sj * 8, &Ks[pg][w * 512]);
  };
  auto stageV = [&](int c, int pg) {
    const int r = w * 8 + srow;          // d-row of V^T
    gload_lds16(vbase + (size_t)r * 4096 + c * 64 + sj * 8, &Vs[pg][w * 512]);
  };

  f32x4 acco[4] = {};
  float m_ = -1e30f, l_ = 0.f;           // per-lane state for q = l15

  const int key = l15 & 7;
  const int ck0 = lhi ^ key;
  const int swr = key << 3;

  stageK(0, 0); stageV(0, 0);
  __syncthreads();
  int cur = 0;
  for (int c = 0; c < 8; ++c) {
    if (c + 1 < 8) { stageK(c + 1, cur ^ 1); stageV(c + 1, cur ^ 1); }
    // --- QK^T swapped: accs row(reg)=s, col(l15)=q ---
    f32x4 accs[4] = {};
    __builtin_amdgcn_s_setprio(1);
    #pragma unroll
    for (int n = 0; n < 4; ++n) {
      const int row = n * 16 + l15;
      half8 kf0 = *(const half8*)&Ks[cur][row * 64 + ck0 * 8];
      half8 kf1 = *(const half8*)&Ks[cur][row * 64 + (ck0 ^ 4) * 8];
      accs[n] = __builtin_amdgcn_mfma_f32_16x16x32_f16(kf0, aq0, accs[n], 0, 0, 0);
      accs[n] = __builtin_amdgcn_mfma_f32_16x16x32_f16(kf1, aq1, accs[n], 0, 0, 0);
    }
    __builtin_amdgcn_s_setprio(0);
    // --- lane-local online softmax for q = l15 ---
    float c0 = fmaxf(fmaxf(accs[0][0], accs[0][1]), fmaxf(accs[0][2], accs[0][3]));
    float c1 = fmaxf(fmaxf(accs[1][0], accs[1][1]), fmaxf(accs[1][2], accs[1][3]));
    float c2 = fmaxf(fmaxf(accs[2][0], accs[2][1]), fmaxf(accs[2][2], accs[2][3]));
    float c3 = fmaxf(fmaxf(accs[3][0], accs[3][1]), fmaxf(accs[3][2], accs[3][3]));
    float mx = fmaxf(fmaxf(c0, c1), fmaxf(c2, c3));
    mx = fmaxf(mx, __shfl_xor(mx, 16, 64));
    mx = fmaxf(mx, __shfl_xor(mx, 32, 64));
    const float mnew = fmaxf(m_, mx);
    const float scale = __expf(m_ - mnew);
    m_ = mnew;
    #pragma unroll
    for (int n = 0; n < 4; ++n)
      #pragma unroll
      for (int r = 0; r < 4; ++r)
        accs[n][r] = __expf(accs[n][r] - mnew);
    float s0 = (accs[0][0] + accs[0][1]) + (accs[0][2] + accs[0][3]);
    float s1 = (accs[1][0] + accs[1][1]) + (accs[1][2] + accs[1][3]);
    float s2 = (accs[2][0] + accs[2][1]) + (accs[2][2] + accs[2][3]);
    float s3 = (accs[3][0] + accs[3][1]) + (accs[3][2] + accs[3][3]);
    float sm = (s0 + s1) + (s2 + s3);
    sm += __shfl_xor(sm, 16, 64);
    sm += __shfl_xor(sm, 32, 64);
    l_ = l_ * scale + sm;
    // --- P write: row q=l15, col s=n*16+lhi*4+r, half4, XOR-swizzled ---
    #pragma unroll
    for (int n = 0; n < 4; ++n) {
      half4v pw;
      pw[0] = (_Float16)accs[n][0]; pw[1] = (_Float16)accs[n][1];
      pw[2] = (_Float16)accs[n][2]; pw[3] = (_Float16)accs[n][3];
      const int base = (n * 16 + lhi * 4) ^ swr;
      *(half4v*)&P[w][l15 * 64 + base] = pw;
    }
    // --- acco rescale (broadcast from lane q) ---
    #pragma unroll
    for (int r = 0; r < 4; ++r) {
      const float s_r = __shfl(scale, (lane >> 4) * 4 + r, 16);
      #pragma unroll
      for (int n = 0; n < 4; ++n) acco[n][r] *= s_r;
    }
    // --- PV partial ---
    __builtin_amdgcn_s_setprio(1);
    #pragma unroll
    for (int ks = 0; ks < 2; ++ks) {
      half8 ap = *(const half8*)&P[w][l15 * 64 + ((ks * 32 + lhi * 8) ^ swr)];
      #pragma unroll
      for (int n = 0; n < 4; ++n) {
        const int row = n * 16 + l15;
        half8 vf = *(const half8*)&Vs[cur][row * 64 + ((ks * 4 + lhi) ^ key) * 8];
        acco[n] = __builtin_amdgcn_mfma_f32_16x16x32_f16(ap, vf, acco[n], 0, 0, 0);
      }
    }
    __builtin_amdgcn_s_setprio(0);
    __syncthreads();
    cur ^= 1;
  }
  // --- finalize: chunk-XOR staging (conflict-free read-back) ---
  const float inv = 1.0f / (l_ * 8.0f);
  #pragma unroll
  for (int r = 0; r < 4; ++r) {
    const float inv_r = __shfl(inv, (lane >> 4) * 4 + r, 16);
    const int qrow = lhi * 4 + r;
    const int kq = qrow & 7;
    #pragma unroll
    for (int n = 0; n < 4; ++n) {
      const int d = n * 16 + l15;
      P[w][qrow * 64 + (((d >> 3) ^ kq) * 8) + (d & 7)] =
          (_Float16)(acco[n][r] * inv_r);
    }
  }
  const int q2 = lane >> 2;
  const int kq2 = q2 & 7;
  const int g0 = ((lane & 3) * 2) ^ kq2;
  const int g1 = ((lane & 3) * 2 + 1) ^ kq2;
  half8 o0 = *(const half8*)&P[w][q2 * 64 + g0 * 8];
  half8 o1 = *(const half8*)&P[w][q2 * 64 + g1 * 8];
  _Float16* op = ao + (size_t)(b * TT + t0 + q2) * HID + h * DH + (lane & 3) * 16;
  *(half8*)op = o0;
  *(half8*)(op + 8) = o1;
}

extern "C" void kernel_launch(void* const* d_in, const int* in_sizes, int n_in,
                              void* d_out, int out_size, void* d_ws, size_t ws_size,
                              hipStream_t stream) {
  const float* x     = (const float*)d_in[0];
  const float* media = (const float*)d_in[1];
  // d_in[2] media_locations: unused (reference discards the mask)
  const float* Wq    = (const float*)d_in[3];
  const float* Wkv   = (const float*)d_in[4];
  const float* Wo    = (const float*)d_in[5];
  const float* gamma = (const float*)d_in[6];
  const float* beta  = (const float*)d_in[7];
  float* out = (float*)d_out;

  char* ws = (char*)d_ws;
  _Float16* xn     = (_Float16*)(ws);                    // 8192x2048 (32MB)
  _Float16* qh     = (_Float16*)(ws + 33554432);         // 8192x1024 (16MB)
  _Float16* kh     = (_Float16*)(ws + 50331648);         // 4096x1024 (8MB)
  _Float16* vth    = (_Float16*)(ws + 58720256);         // 1024x4096 (8MB)
  _Float16* aoh    = (_Float16*)(ws + 67108864);         // 8192x1024 (16MB)
  _Float16* mediah = (_Float16*)(ws + 83886080);         // 4096x1024 (8MB)
  _Float16* wqT    = (_Float16*)(ws + 92274688);         // 1024x2048 (4MB)
  _Float16* wkvT   = (_Float16*)(ws + 96468992);         // 2048x1024 (4MB)
  _Float16* woT    = (_Float16*)(ws + 100663296);        // 2048x1024 (4MB)

  ln_cast<<<dim3(8192), dim3(256), 0, stream>>>(x, gamma, beta, xn);
  transpose_cast<<<dim3(1024/32, 2048/32), dim3(32, 8), 0, stream>>>(Wq,  wqT,  2048, 1024);
  transpose_cast<<<dim3(2048/32, 1024/32), dim3(32, 8), 0, stream>>>(Wkv, wkvT, 1024, 2048);
  transpose_cast<<<dim3(2048/32, 1024/32), dim3(32, 8), 0, stream>>>(Wo,  woT,  1024, 2048);
  cast_f16<<<dim3(4096), dim3(256), 0, stream>>>(media, mediah, 4194304 / 4);

  gemm_qkv<<<dim3(1024), dim3(256), 0, stream>>>(xn, wqT, qh, mediah, wkvT, kh, vth);
  attn_kernel<<<dim3(1024), dim3(512), 0, stream>>>(qh, kh, vth, aoh);
  gemm_out<<<dim3(1024), dim3(256), 0, stream>>>(aoh, woT, out);
}

// Round 10
// 177.147 us; speedup vs baseline: 1.4278x; 1.0347x over previous
//
#include <hip/hip_runtime.h>
#include <hip/hip_bf16.h>
#include <stdint.h>

#define B_     8
#define TT     1024
#define DIM_   2048
#define S_     512
#define H_     16
#define DH     64
#define HID    1024

typedef _Float16 half8 __attribute__((ext_vector_type(8)));
typedef _Float16 half4v __attribute__((ext_vector_type(4)));
typedef float f32x4 __attribute__((ext_vector_type(4)));

__device__ __forceinline__ void gload_lds16(const void* g, void* l) {
  __builtin_amdgcn_global_load_lds(
      (__attribute__((address_space(1))) unsigned int*)(uintptr_t)g,
      (__attribute__((address_space(3))) unsigned int*)l, 16, 0, 0);
}

#define MFMA16(afv, bfv, nh)                                                  \
  do {                                                                        \
    __builtin_amdgcn_s_setprio(1);                                            \
    _Pragma("unroll")                                                         \
    for (int m_ = 0; m_ < 8; ++m_) {                                          \
      acc[m_][(nh)*2]   = __builtin_amdgcn_mfma_f32_16x16x32_f16(             \
          afv[m_], bfv[0], acc[m_][(nh)*2], 0, 0, 0);                         \
      acc[m_][(nh)*2+1] = __builtin_amdgcn_mfma_f32_16x16x32_f16(             \
          afv[m_], bfv[1], acc[m_][(nh)*2+1], 0, 0, 0);                       \
    }                                                                         \
    __builtin_amdgcn_s_setprio(0);                                            \
  } while (0)

// ---------------- LayerNorm + cast to fp16 ----------------
__global__ __launch_bounds__(256) void ln_cast(
    const float* __restrict__ x, const float* __restrict__ gamma,
    const float* __restrict__ beta, _Float16* __restrict__ xn)
{
  const int row = blockIdx.x;
  const int tid = threadIdx.x;
  const float* xr = x + (size_t)row * DIM_;
  float4 a = ((const float4*)xr)[tid * 2];
  float4 b = ((const float4*)xr)[tid * 2 + 1];
  float s1 = a.x + a.y + a.z + a.w + b.x + b.y + b.z + b.w;
  float s2 = a.x*a.x + a.y*a.y + a.z*a.z + a.w*a.w
           + b.x*b.x + b.y*b.y + b.z*b.z + b.w*b.w;
  #pragma unroll
  for (int d = 1; d < 64; d <<= 1) {
    s1 += __shfl_xor(s1, d, 64);
    s2 += __shfl_xor(s2, d, 64);
  }
  __shared__ float red[8];
  const int w = tid >> 6, lane = tid & 63;
  if (lane == 0) { red[w] = s1; red[4 + w] = s2; }
  __syncthreads();
  s1 = red[0] + red[1] + red[2] + red[3];
  s2 = red[4] + red[5] + red[6] + red[7];
  const float mu  = s1 * (1.0f / DIM_);
  const float var = s2 * (1.0f / DIM_) - mu * mu;
  const float rs  = rsqrtf(var + 1e-5f);
  float4 g0 = ((const float4*)gamma)[tid * 2];
  float4 g1 = ((const float4*)gamma)[tid * 2 + 1];
  float4 e0 = ((const float4*)beta)[tid * 2];
  float4 e1 = ((const float4*)beta)[tid * 2 + 1];
  half8 o;
  o[0] = (_Float16)((a.x - mu) * rs * g0.x + e0.x);
  o[1] = (_Float16)((a.y - mu) * rs * g0.y + e0.y);
  o[2] = (_Float16)((a.z - mu) * rs * g0.z + e0.z);
  o[3] = (_Float16)((a.w - mu) * rs * g0.w + e0.w);
  o[4] = (_Float16)((b.x - mu) * rs * g1.x + e1.x);
  o[5] = (_Float16)((b.y - mu) * rs * g1.y + e1.y);
  o[6] = (_Float16)((b.z - mu) * rs * g1.z + e1.z);
  o[7] = (_Float16)((b.w - mu) * rs * g1.w + e1.w);
  *(half8*)(xn + (size_t)row * DIM_ + tid * 8) = o;
}

// ---------------- elementwise f32 -> f16 cast ----------------
__global__ __launch_bounds__(256) void cast_f16(
    const float* __restrict__ in, _Float16* __restrict__ out, int n4)
{
  int i = blockIdx.x * 256 + threadIdx.x;
  if (i >= n4) return;
  float4 v = ((const float4*)in)[i];
  half4v o;
  o[0] = (_Float16)v.x; o[1] = (_Float16)v.y;
  o[2] = (_Float16)v.z; o[3] = (_Float16)v.w;
  ((half4v*)out)[i] = o;
}

// ---------------- transpose + cast: in[R][C] f32 -> out[C][R] f16 ----------------
__global__ void transpose_cast(const float* __restrict__ in,
                               _Float16* __restrict__ out, int R, int C)
{
  __shared__ float t[32][33];
  const int c0 = blockIdx.x * 32, r0 = blockIdx.y * 32;
  const int tx = threadIdx.x, ty = threadIdx.y;
  #pragma unroll
  for (int i = 0; i < 32; i += 8)
    t[ty + i][tx] = in[(size_t)(r0 + ty + i) * C + c0 + tx];
  __syncthreads();
  #pragma unroll
  for (int i = 0; i < 32; i += 8)
    out[(size_t)(c0 + ty + i) * R + r0 + tx] = (_Float16)t[tx][ty + i];
}

// ---------------- 256x256 GEMM, BK=64, 8 waves, 8-phase counted-vmcnt ------
// C[M][N] = A[M][K] @ BT[N][K]^T. Even/odd K-tile buffers (32KB each per
// operand, 128KB total -> 1 block/CU). Per iter (2 K-tiles), 8 phases of
// {ds_read frags | stage 1 half-tile (2 gloads) | barrier | lgkmcnt(0) |
// setprio | 16 MFMA | setprio | barrier}. Reads: ph1: A kh0 + B kh0 n01;
// ph2: A kh1 + B kh0 n23; ph3: B kh1 n01; ph4: B kh1 n23 (A free after ph2,
// B after ph4). Stage slots ph1..8 = [Bh0(t1), Bh1(t1), Ah0(t0+2), Ah1(t0+2),
// Bh0(t0+2), Bh1(t0+2), Ah0(t1+2), Ah1(t1+2)] - every overwrite >=1 barrier
// after its last reader. vmcnt(4) only at ph4/ph8 (newest 2 half-tiles may
// stay in flight); tail iterations drain to vmcnt(0). 8-chunk XOR swizzle
// (measured 0-conflict pattern) on stage source + frag reads.
template<int KD, int ND, typename OutT>
__device__ __forceinline__ void gemm256_body(
    const _Float16* __restrict__ A, const _Float16* __restrict__ BT,
    OutT* __restrict__ C, int m0, int n0,
    _Float16* __restrict__ sAe, _Float16* __restrict__ sAo,
    _Float16* __restrict__ sBe, _Float16* __restrict__ sBo)
{
  constexpr int NT = KD / 64;
  constexpr int NI = NT / 2;
  const int tid = threadIdx.x;
  const int lane = tid & 63, w = tid >> 6;
  const int l15 = lane & 15, lhi = lane >> 4;
  const int wr = w >> 2, wc = w & 3;          // 2 x 4 wave grid
  const int rs = l15 & 7;                     // frag-read swizzle key
  const int srow = tid >> 3;                  // staging row 0..63
  const int sch = (tid & 7) ^ (srow & 7);     // pre-swizzled source chunk

  // stage half h (rows h*128..+127) of K-tile kt into tile buffer dst
  auto stage = [&](const _Float16* __restrict__ G, int base, int kt, int h,
                   _Float16* __restrict__ dst) {
    #pragma unroll
    for (int j = 0; j < 2; ++j) {
      const int r = h * 128 + j * 64 + srow;
      gload_lds16(G + (size_t)(base + r) * KD + kt * 64 + sch * 8,
                  dst + h * 8192 + j * 4096 + w * 512);
    }
  };

  f32x4 acc[8][4] = {};
  half8 af0[8], af1[8], bf0[2], bf1[2];

  // ---- prologue: t0 full + t1 A-halves; vmcnt(4) keeps A(1) in flight ----
  stage(A,  m0, 0, 0, sAe); stage(A,  m0, 0, 1, sAe);
  stage(BT, n0, 0, 0, sBe); stage(BT, n0, 0, 1, sBe);
  stage(A,  m0, 1, 0, sAo); stage(A,  m0, 1, 1, sAo);
  asm volatile("s_waitcnt vmcnt(4)" ::: "memory");
  __builtin_amdgcn_s_barrier();

  for (int it = 0; it < NI; ++it) {
    const bool pf = (it + 1 < NI);
    const int t1 = 2 * it + 1, tn0 = 2 * it + 2, tn1 = 2 * it + 3;

    // ================= even tile (sAe/sBe) : phases 1-4 =================
    // ph1: read A kh0 + B kh0 n01 ; stage Bh0(t1)
    #pragma unroll
    for (int m = 0; m < 8; ++m)
      af0[m] = *(const half8*)&sAe[(wr*128 + m*16 + l15)*64 + ((lhi ^ rs)*8)];
    #pragma unroll
    for (int n = 0; n < 2; ++n)
      bf0[n] = *(const half8*)&sBe[(wc*64 + n*16 + l15)*64 + ((lhi ^ rs)*8)];
    stage(BT, n0, t1, 0, sBo);
    __builtin_amdgcn_s_barrier();
    asm volatile("s_waitcnt lgkmcnt(0)" ::: "memory");
    MFMA16(af0, bf0, 0);
    __builtin_amdgcn_s_barrier();
    // ph2: read A kh1 + B kh0 n23 ; stage Bh1(t1)
    #pragma unroll
    for (int m = 0; m < 8; ++m)
      af1[m] = *(const half8*)&sAe[(wr*128 + m*16 + l15)*64 + (((4+lhi) ^ rs)*8)];
    #pragma unroll
    for (int n = 0; n < 2; ++n)
      bf1[n] = *(const half8*)&sBe[(wc*64 + (2+n)*16 + l15)*64 + ((lhi ^ rs)*8)];
    stage(BT, n0, t1, 1, sBo);
    __builtin_amdgcn_s_barrier();
    asm volatile("s_waitcnt lgkmcnt(0)" ::: "memory");
    MFMA16(af0, bf1, 1);
    __builtin_amdgcn_s_barrier();
    // ph3: read B kh1 n01 ; stage Ah0(t0+2)
    #pragma unroll
    for (int n = 0; n < 2; ++n)
      bf0[n] = *(const half8*)&sBe[(wc*64 + n*16 + l15)*64 + (((4+lhi) ^ rs)*8)];
    if (pf) stage(A, m0, tn0, 0, sAe);
    __builtin_amdgcn_s_barrier();
    asm volatile("s_waitcnt lgkmcnt(0)" ::: "memory");
    MFMA16(af1, bf0, 0);
    __builtin_amdgcn_s_barrier();
    // ph4: read B kh1 n23 ; stage Ah1(t0+2) ; checkpoint
    #pragma unroll
    for (int n = 0; n < 2; ++n)
      bf1[n] = *(const half8*)&sBe[(wc*64 + (2+n)*16 + l15)*64 + (((4+lhi) ^ rs)*8)];
    if (pf) stage(A, m0, tn0, 1, sAe);
    __builtin_amdgcn_s_barrier();
    asm volatile("s_waitcnt lgkmcnt(0)" ::: "memory");
    MFMA16(af1, bf1, 1);
    if (pf) asm volatile("s_waitcnt vmcnt(4)" ::: "memory");
    else    asm volatile("s_waitcnt vmcnt(0)" ::: "memory");
    __builtin_amdgcn_s_barrier();

    // ================= odd tile (sAo/sBo) : phases 5-8 ==================
    // ph5: read A kh0 + B kh0 n01 ; stage Bh0(t0+2)
    #pragma unroll
    for (int m = 0; m < 8; ++m)
      af0[m] = *(const half8*)&sAo[(wr*128 + m*16 + l15)*64 + ((lhi ^ rs)*8)];
    #pragma unroll
    for (int n = 0; n < 2; ++n)
      bf0[n] = *(const half8*)&sBo[(wc*64 + n*16 + l15)*64 + ((lhi ^ rs)*8)];
    if (pf) stage(BT, n0, tn0, 0, sBe);
    __builtin_amdgcn_s_barrier();
    asm volatile("s_waitcnt lgkmcnt(0)" ::: "memory");
    MFMA16(af0, bf0, 0);
    __builtin_amdgcn_s_barrier();
    // ph6: read A kh1 + B kh0 n23 ; stage Bh1(t0+2)
    #pragma unroll
    for (int m = 0; m < 8; ++m)
      af1[m] = *(const half8*)&sAo[(wr*128 + m*16 + l15)*64 + (((4+lhi) ^ rs)*8)];
    #pragma unroll
    for (int n = 0; n < 2; ++n)
      bf1[n] = *(const half8*)&sBo[(wc*64 + (2+n)*16 + l15)*64 + ((lhi ^ rs)*8)];
    if (pf) stage(BT, n0, tn0, 1, sBe);
    __builtin_amdgcn_s_barrier();
    asm volatile("s_waitcnt lgkmcnt(0)" ::: "memory");
    MFMA16(af0, bf1, 1);
    __builtin_amdgcn_s_barrier();
    // ph7: read B kh1 n01 ; stage Ah0(t1+2)
    #pragma unroll
    for (int n = 0; n < 2; ++n)
      bf0[n] = *(const half8*)&sBo[(wc*64 + n*16 + l15)*64 + (((4+lhi) ^ rs)*8)];
    if (pf) stage(A, m0, tn1, 0, sAo);
    __builtin_amdgcn_s_barrier();
    asm volatile("s_waitcnt lgkmcnt(0)" ::: "memory");
    MFMA16(af1, bf0, 0);
    __builtin_amdgcn_s_barrier();
    // ph8: read B kh1 n23 ; stage Ah1(t1+2) ; checkpoint
    #pragma unroll
    for (int n = 0; n < 2; ++n)
      bf1[n] = *(const half8*)&sBo[(wc*64 + (2+n)*16 + l15)*64 + (((4+lhi) ^ rs)*8)];
    if (pf) stage(A, m0, tn1, 1, sAo);
    __builtin_amdgcn_s_barrier();
    asm volatile("s_waitcnt lgkmcnt(0)" ::: "memory");
    MFMA16(af1, bf1, 1);
    if (pf) asm volatile("s_waitcnt vmcnt(4)" ::: "memory");
    else    asm volatile("s_waitcnt vmcnt(0)" ::: "memory");
    __builtin_amdgcn_s_barrier();
  }

  #pragma unroll
  for (int mf = 0; mf < 8; ++mf) {
    const int row = m0 + wr * 128 + mf * 16 + lhi * 4;
    #pragma unroll
    for (int nf = 0; nf < 4; ++nf) {
      const int col = n0 + wc * 64 + nf * 16 + l15;
      #pragma unroll
      for (int r = 0; r < 4; ++r)
        C[(size_t)(row + r) * ND + col] = (OutT)acc[mf][nf][r];
    }
  }
}

// Fused Q-proj (128) + K-proj (64) + V^T-proj (64) = 256 blocks = 1/CU.
// XCD: id%8 == m%8 within each sub-grid -> A m-panels XCD-local.
__global__ __launch_bounds__(512, 2) void gemm_qkv(
    const _Float16* __restrict__ xn, const _Float16* __restrict__ wqT,
    _Float16* __restrict__ qh,
    const _Float16* __restrict__ mediah, const _Float16* __restrict__ wkvT,
    _Float16* __restrict__ kh, _Float16* __restrict__ vth)
{
  __shared__ __align__(16) _Float16 sAe[256 * 64], sAo[256 * 64];
  __shared__ __align__(16) _Float16 sBe[256 * 64], sBo[256 * 64];
  const int id = blockIdx.x;
  if (id < 128) {              // Q: M=8192 N=1024 K=2048 (32 x 4 tiles)
    const int m = id & 31, n = id >> 5;
    gemm256_body<2048, 1024, _Float16>(xn, wqT, qh, m * 256, n * 256,
                                       sAe, sAo, sBe, sBo);
  } else if (id < 192) {       // K: M=4096 N=1024 K=1024 (16 x 4 tiles)
    const int lid = id - 128;
    const int m = lid & 15, n = lid >> 4;
    gemm256_body<1024, 1024, _Float16>(mediah, wkvT, kh, m * 256, n * 256,
                                       sAe, sAo, sBe, sBo);
  } else {                     // V^T: M=1024 N=4096 K=1024 (4 x 16 tiles)
    const int lid = id - 192;
    const int m = lid & 3, n = lid >> 2;
    gemm256_body<1024, 4096, _Float16>(wkvT + 1024 * 1024, mediah, vth,
                                       m * 256, n * 256, sAe, sAo, sBe, sBo);
  }
}

// Out-proj: M=8192 N=2048 K=1024 -> 32 x 8 = 256 blocks = 1/CU, f32 out.
__global__ __launch_bounds__(512, 2) void gemm_out(
    const _Float16* __restrict__ aoh, const _Float16* __restrict__ woT,
    float* __restrict__ out)
{
  __shared__ __align__(16) _Float16 sAe[256 * 64], sAo[256 * 64];
  __shared__ __align__(16) _Float16 sBe[256 * 64], sBo[256 * 64];
  const int id = blockIdx.x;
  const int m = id & 31, n = id >> 5;
  gemm256_body<1024, 2048, float>(aoh, woT, out, m * 256, n * 256,
                                  sAe, sAo, sBe, sBo);
}

// ---------------- fused attention v6: swapped QK^T, lane-local softmax ----
// (round-9 attn; K from kh [B*S][1024], V^T from vth [1024][4096])
__global__ __launch_bounds__(512, 6) void attn_kernel(
    const _Float16* __restrict__ q, const _Float16* __restrict__ kh,
    const _Float16* __restrict__ vt, _Float16* __restrict__ ao)
{
  __shared__ __align__(16) _Float16 Ks[2][64 * 64];   // 8 KB each
  __shared__ __align__(16) _Float16 Vs[2][64 * 64];   // 8 KB each
  __shared__ __align__(16) _Float16 P[8][16 * 64];    // 16 KB (per-wave 2KB)
  const int tid = threadIdx.x;
  const int lane = tid & 63, w = tid >> 6;
  const int l15 = lane & 15, lhi = lane >> 4;
  const int id = blockIdx.x;
  const int bh = id & 127, tb = id >> 7;
  const int b = bh >> 4, h = bh & 15;
  const int t0 = tb * 128 + w * 16;

  const _Float16* qp = q + (size_t)(b * TT + t0 + l15) * HID + h * DH + lhi * 8;
  half8 aq0 = *(const half8*)qp;
  half8 aq1 = *(const half8*)(qp + 32);

  const int srow = lane >> 3;
  const int sj   = (lane & 7) ^ srow;
  const _Float16* kbase = kh + (size_t)(b * S_) * 1024 + h * DH;
  const _Float16* vbase = vt + (size_t)(h * DH) * 4096 + b * S_;

  auto stageK = [&](int c, int pg) {
    const int r = w * 8 + srow;
    gload_lds16(kbase + (size_t)(c * 64 + r) * 1024 + sj * 8, &Ks[pg][w * 512]);
  };
  auto stageV = [&](int c, int pg) {
    const int r = w * 8 + srow;          // d-row of V^T
    gload_lds16(vbase + (size_t)r * 4096 + c * 64 + sj * 8, &Vs[pg][w * 512]);
  };

  f32x4 acco[4] = {};
  float m_ = -1e30f, l_ = 0.f;           // per-lane state for q = l15

  const int key = l15 & 7;
  const int ck0 = lhi ^ key;
  const int swr = key << 3;

  stageK(0, 0); stageV(0, 0);
  __syncthreads();
  int cur = 0;
  for (int c = 0; c < 8; ++c) {
    if (c + 1 < 8) { stageK(c + 1, cur ^ 1); stageV(c + 1, cur ^ 1); }
    // --- QK^T swapped: accs row(reg)=s, col(l15)=q ---
    f32x4 accs[4] = {};
    __builtin_amdgcn_s_setprio(1);
    #pragma unroll
    for (int n = 0; n < 4; ++n) {
      const int row = n * 16 + l15;
      half8 kf0 = *(const half8*)&Ks[cur][row * 64 + ck0 * 8];
      half8 kf1 = *(const half8*)&Ks[cur][row * 64 + (ck0 ^ 4) * 8];
      accs[n] = __builtin_amdgcn_mfma_f32_16x16x32_f16(kf0, aq0, accs[n], 0, 0, 0);
      accs[n] = __builtin_amdgcn_mfma_f32_16x16x32_f16(kf1, aq1, accs[n], 0, 0, 0);
    }
    __builtin_amdgcn_s_setprio(0);
    // --- lane-local online softmax for q = l15 ---
    float c0 = fmaxf(fmaxf(accs[0][0], accs[0][1]), fmaxf(accs[0][2], accs[0][3]));
    float c1 = fmaxf(fmaxf(accs[1][0], accs[1][1]), fmaxf(accs[1][2], accs[1][3]));
    float c2 = fmaxf(fmaxf(accs[2][0], accs[2][1]), fmaxf(accs[2][2], accs[2][3]));
    float c3 = fmaxf(fmaxf(accs[3][0], accs[3][1]), fmaxf(accs[3][2], accs[3][3]));
    float mx = fmaxf(fmaxf(c0, c1), fmaxf(c2, c3));
    mx = fmaxf(mx, __shfl_xor(mx, 16, 64));
    mx = fmaxf(mx, __shfl_xor(mx, 32, 64));
    const float mnew = fmaxf(m_, mx);
    const float scale = __expf(m_ - mnew);
    m_ = mnew;
    #pragma unroll
    for (int n = 0; n < 4; ++n)
      #pragma unroll
      for (int r = 0; r < 4; ++r)
        accs[n][r] = __expf(accs[n][r] - mnew);
    float s0 = (accs[0][0] + accs[0][1]) + (accs[0][2] + accs[0][3]);
    float s1 = (accs[1][0] + accs[1][1]) + (accs[1][2] + accs[1][3]);
    float s2 = (accs[2][0] + accs[2][1]) + (accs[2][2] + accs[2][3]);
    float s3 = (accs[3][0] + accs[3][1]) + (accs[3][2] + accs[3][3]);
    float sm = (s0 + s1) + (s2 + s3);
    sm += __shfl_xor(sm, 16, 64);
    sm += __shfl_xor(sm, 32, 64);
    l_ = l_ * scale + sm;
    // --- P write: row q=l15, col s=n*16+lhi*4+r, half4, XOR-swizzled ---
    #pragma unroll
    for (int n = 0; n < 4; ++n) {
      half4v pw;
      pw[0] = (_Float16)accs[n][0]; pw[1] = (_Float16)accs[n][1];
      pw[2] = (_Float16)accs[n][2]; pw[3] = (_Float16)accs[n][3];
      const int base = (n * 16 + lhi * 4) ^ swr;
      *(half4v*)&P[w][l15 * 64 + base] = pw;
    }
    // --- acco rescale (broadcast from lane q) ---
    #pragma unroll
    for (int r = 0; r < 4; ++r) {
      const float s_r = __shfl(scale, (lane >> 4) * 4 + r, 16);
      #pragma unroll
      for (int n = 0; n < 4; ++n) acco[n][r] *= s_r;
    }
    // --- PV partial ---
    __builtin_amdgcn_s_setprio(1);
    #pragma unroll
    for (int ks = 0; ks < 2; ++ks) {
      half8 ap = *(const half8*)&P[w][l15 * 64 + ((ks * 32 + lhi * 8) ^ swr)];
      #pragma unroll
      for (int n = 0; n < 4; ++n) {
        const int row = n * 16 + l15;
        half8 vf = *(const half8*)&Vs[cur][row * 64 + ((ks * 4 + lhi) ^ key) * 8];
        acco[n] = __builtin_amdgcn_mfma_f32_16x16x32_f16(ap, vf, acco[n], 0, 0, 0);
      }
    }
    __builtin_amdgcn_s_setprio(0);
    __syncthreads();
    cur ^= 1;
  }
  // --- finalize: chunk-XOR staging (conflict-free read-back) ---
  const float inv = 1.0f / (l_ * 8.0f);
  #pragma unroll
  for (int r = 0; r < 4; ++r) {
    const float inv_r = __shfl(inv, (lane >> 4) * 4 + r, 16);
    const int qrow = lhi * 4 + r;
    const int kq = qrow & 7;
    #pragma unroll
    for (int n = 0; n < 4; ++n) {
      const int d = n * 16 + l15;
      P[w][qrow * 64 + (((d >> 3) ^ kq) * 8) + (d & 7)] =
          (_Float16)(acco[n][r] * inv_r);
    }
  }
  const int q2 = lane >> 2;
  const int kq2 = q2 & 7;
  const int g0 = ((lane & 3) * 2) ^ kq2;
  const int g1 = ((lane & 3) * 2 + 1) ^ kq2;
  half8 o0 = *(const half8*)&P[w][q2 * 64 + g0 * 8];
  half8 o1 = *(const half8*)&P[w][q2 * 64 + g1 * 8];
  _Float16* op = ao + (size_t)(b * TT + t0 + q2) * HID + h * DH + (lane & 3) * 16;
  *(half8*)op = o0;
  *(half8*)(op + 8) = o1;
}

extern "C" void kernel_launch(void* const* d_in, const int* in_sizes, int n_in,
                              void* d_out, int out_size, void* d_ws, size_t ws_size,
                              hipStream_t stream) {
  const float* x     = (const float*)d_in[0];
  const float* media = (const float*)d_in[1];
  // d_in[2] media_locations: unused (reference discards the mask)
  const float* Wq    = (const float*)d_in[3];
  const float* Wkv   = (const float*)d_in[4];
  const float* Wo    = (const float*)d_in[5];
  const float* gamma = (const float*)d_in[6];
  const float* beta  = (const float*)d_in[7];
  float* out = (float*)d_out;

  char* ws = (char*)d_ws;
  _Float16* xn     = (_Float16*)(ws);                    // 8192x2048 (32MB)
  _Float16* qh     = (_Float16*)(ws + 33554432);         // 8192x1024 (16MB)
  _Float16* kh     = (_Float16*)(ws + 50331648);         // 4096x1024 (8MB)
  _Float16* vth    = (_Float16*)(ws + 58720256);         // 1024x4096 (8MB)
  _Float16* aoh    = (_Float16*)(ws + 67108864);         // 8192x1024 (16MB)
  _Float16* mediah = (_Float16*)(ws + 83886080);         // 4096x1024 (8MB)
  _Float16* wqT    = (_Float16*)(ws + 92274688);         // 1024x2048 (4MB)
  _Float16* wkvT   = (_Float16*)(ws + 96468992);         // 2048x1024 (4MB)
  _Float16* woT    = (_Float16*)(ws + 100663296);        // 2048x1024 (4MB)

  ln_cast<<<dim3(8192), dim3(256), 0, stream>>>(x, gamma, beta, xn);
  transpose_cast<<<dim3(1024/32, 2048/32), dim3(32, 8), 0, stream>>>(Wq,  wqT,  2048, 1024);
  transpose_cast<<<dim3(2048/32, 1024/32), dim3(32, 8), 0, stream>>>(Wkv, wkvT, 1024, 2048);
  transpose_cast<<<dim3(2048/32, 1024/32), dim3(32, 8), 0, stream>>>(Wo,  woT,  1024, 2048);
  cast_f16<<<dim3(4096), dim3(256), 0, stream>>>(media, mediah, 4194304 / 4);

  gemm_qkv<<<dim3(256), dim3(512), 0, stream>>>(xn, wqT, qh, mediah, wkvT, kh, vth);
  attn_kernel<<<dim3(1024), dim3(512), 0, stream>>>(qh, kh, vth, aoh);
  gemm_out<<<dim3(256), dim3(512), 0, stream>>>(aoh, woT, out);
}